// Round 2
// 1279.141 us; speedup vs baseline: 1.0887x; 1.0887x over previous
//
#include <hip/hip_runtime.h>
#include <stdint.h>

// BitLinear: x[4,2048,4096] fp32, w[16384,4096] fp32 -> out[4,2048,16384] fp32
// M = 8192 tokens, N = 16384, K = 4096.
// Exact int8 path: C = s_m * gamma * (int8 dot ternary), i32 accum exact.

#define M_DIM 8192
#define N_DIM 16384
#define K_DIM 4096
#define W_ELEMS (N_DIM * K_DIM)   // 67108864
#define X_ELEMS (M_DIM * K_DIM)   // 33554432

typedef int v4i __attribute__((ext_vector_type(4)));

// workspace layout (bytes)
#define WS_GSUM   0u            // double
#define WS_SCALES 256u          // float[8192]
#define WS_XQ     65536u        // int8[M][K] = 33554432 B
#define WS_WQ     33685504u     // int8[N][K] = 67108864 B  (total ~96.1 MiB)

// ---------------- gamma = max(mean |w|, 1e-6) ----------------
__global__ __launch_bounds__(256) void k_gamma(const float4* __restrict__ w,
                                               double* __restrict__ gsum) {
    int tid = blockIdx.x * 256 + threadIdx.x;
    int stride = gridDim.x * 256;
    float s = 0.f;
    for (int i = tid; i < W_ELEMS / 4; i += stride) {
        float4 v = w[i];
        s += fabsf(v.x) + fabsf(v.y) + fabsf(v.z) + fabsf(v.w);
    }
    #pragma unroll
    for (int off = 32; off; off >>= 1) s += __shfl_down(s, off, 64);
    __shared__ float wsum[4];
    int lane = threadIdx.x & 63, wv = threadIdx.x >> 6;
    if (lane == 0) wsum[wv] = s;
    __syncthreads();
    if (threadIdx.x == 0) {
        double t = (double)wsum[0] + (double)wsum[1] + (double)wsum[2] + (double)wsum[3];
        atomicAdd(gsum, t);
    }
}

__device__ __forceinline__ int pack4i8(float a, float b, float c, float d) {
    int ia = (int)a & 0xFF, ib = (int)b & 0xFF, ic = (int)c & 0xFF, id = (int)d & 0xFF;
    return ia | (ib << 8) | (ic << 16) | (id << 24);
}

// ---------------- wq = round(clip(w/gamma, -1, 1)) as int8 ----------------
__global__ __launch_bounds__(256) void k_wq(const float4* __restrict__ w,
                                            const double* __restrict__ gsum,
                                            int* __restrict__ wq4) {
    float g = fmaxf((float)(*gsum * (1.0 / 67108864.0)), 1e-6f);
    int tid = blockIdx.x * 256 + threadIdx.x;
    int stride = gridDim.x * 256;
    for (int i = tid; i < W_ELEMS / 4; i += stride) {
        float4 v = w[i];
        float qa = rintf(fminf(fmaxf(v.x / g, -1.f), 1.f));
        float qb = rintf(fminf(fmaxf(v.y / g, -1.f), 1.f));
        float qc = rintf(fminf(fmaxf(v.z / g, -1.f), 1.f));
        float qd = rintf(fminf(fmaxf(v.w / g, -1.f), 1.f));
        wq4[i] = pack4i8(qa, qb, qc, qd);
    }
}

// ---------------- per-token act quant ----------------
__global__ __launch_bounds__(256) void k_xq(const float4* __restrict__ x,
                                            int* __restrict__ xq4,
                                            float* __restrict__ scales) {
    int token = blockIdx.x;
    int t = threadIdx.x;
    const float4* xrow = x + (size_t)token * (K_DIM / 4);
    float4 v[4];
    float m = 0.f;
    #pragma unroll
    for (int i = 0; i < 4; i++) {
        v[i] = xrow[i * 256 + t];
        m = fmaxf(m, fmaxf(fmaxf(fabsf(v[i].x), fabsf(v[i].y)),
                           fmaxf(fabsf(v[i].z), fabsf(v[i].w))));
    }
    #pragma unroll
    for (int off = 32; off; off >>= 1) m = fmaxf(m, __shfl_xor(m, off, 64));
    __shared__ float wm[4];
    int lane = t & 63, wv = t >> 6;
    if (lane == 0) wm[wv] = m;
    __syncthreads();
    m = fmaxf(fmaxf(wm[0], wm[1]), fmaxf(wm[2], wm[3]));
    float s = fmaxf(m / 127.0f, 1e-8f);
    int* orow = xq4 + (size_t)token * (K_DIM / 4);
    #pragma unroll
    for (int i = 0; i < 4; i++) {
        float qa = fminf(fmaxf(rintf(v[i].x / s), -127.f), 127.f);
        float qb = fminf(fmaxf(rintf(v[i].y / s), -127.f), 127.f);
        float qc = fminf(fmaxf(rintf(v[i].z / s), -127.f), 127.f);
        float qd = fminf(fmaxf(rintf(v[i].w / s), -127.f), 127.f);
        orow[i * 256 + t] = pack4i8(qa, qb, qc, qd);
    }
    if (t == 0) scales[token] = s;
}

// ---------------- i8 GEMM: 256x256 tile, BK=64, ring-4 LDS, counted vmcnt ----------------
// 8 waves (2M x 4N), per-wave 128x64 output, mfma_i32_16x16x64_i8.
// LDS XOR-swizzle: logical 16B slot s of row r stored at physical slot s ^ ((r>>1)&3).
// Applied on BOTH sides: pre-swizzled global source (global_load_lds writes linearly)
// and swizzled ds_read offsets -> balanced 8 lanes/16B-quad (conflict-free b128).

#define BK 64
#define NT (K_DIM / BK)   // 64 K-tiles

#define ASYNC_CP16(g, l)                                                              \
    __builtin_amdgcn_global_load_lds((const __attribute__((address_space(1))) void*)(g), \
                                     (__attribute__((address_space(3))) void*)(l), 16, 0, 0)
#define WAITV(n) asm volatile("s_waitcnt vmcnt(" #n ")" ::: "memory")
#define BARRIER() do { asm volatile("" ::: "memory");       \
                       __builtin_amdgcn_s_barrier();        \
                       asm volatile("" ::: "memory"); } while (0)

__global__ __launch_bounds__(512, 2) void k_gemm(const char* __restrict__ A,
                                                 const char* __restrict__ B,
                                                 const float* __restrict__ scales,
                                                 const double* __restrict__ gsum,
                                                 float* __restrict__ C) {
    // ring of 4 K-tiles per operand: 4 * 256*64 B * 2 = 128 KiB
    __shared__ __align__(16) char As[4][256 * BK];
    __shared__ __align__(16) char Bs[4][256 * BK];

    const int t = threadIdx.x;
    const int w = t >> 6;            // wave 0..7
    const int l = t & 63;            // lane
    const int m0 = blockIdx.y * 256;
    const int n0 = blockIdx.x * 256;

    // ---- staging addresses: per tile 4 global_load_lds per wave (A j0,A j1,B j0,B j1)
    // wave-load j covers 16 rows (1 KiB): rows (j*8+w)*16 + (l>>2), phys slot l&3.
    // logical source slot for this phys position: (l&3) ^ ((row>>1)&3) = (l&3)^((l>>3)&3)
    const int srow = l >> 2;                          // 0..15
    const int sslot = (l & 3) ^ ((l >> 3) & 3);
    const char* gA0 = A + (size_t)(m0 + w * 16 + srow) * K_DIM + sslot * 16;
    const char* gA1 = gA0 + (size_t)128 * K_DIM;
    const char* gB0 = B + (size_t)(n0 + w * 16 + srow) * K_DIM + sslot * 16;
    const char* gB1 = gB0 + (size_t)128 * K_DIM;
    const int ldsOff = w * 1024 + l * 16;             // + j*8192, wave-uniform base + lane*16

#define STAGE_A(kt, buf) do {                              \
        ASYNC_CP16(gA0 + (size_t)(kt) * BK, &As[buf][ldsOff]);        \
        ASYNC_CP16(gA1 + (size_t)(kt) * BK, &As[buf][8192 + ldsOff]); } while (0)
#define STAGE_B(kt, buf) do {                              \
        ASYNC_CP16(gB0 + (size_t)(kt) * BK, &Bs[buf][ldsOff]);        \
        ASYNC_CP16(gB1 + (size_t)(kt) * BK, &Bs[buf][8192 + ldsOff]); } while (0)

    // ---- fragment read offsets (swizzled)
    const int wm = w >> 2;           // 0..1 : rows wm*128..+127
    const int wn = w & 3;            // 0..3 : cols wn*64..+63
    const int r16 = l & 15;
    const int kq = l >> 4;           // 0..3 : which 16B k-slice
    const int swz = ((kq ^ ((r16 >> 1) & 3)) << 4);
    const int aoff = (wm * 128 + r16) * BK + swz;    // + mi*1024 per m-frag
    const int boff = (wn * 64 + r16) * BK + swz;     // + nj*1024 per n-frag

    v4i acc[8][4];
    #pragma unroll
    for (int i = 0; i < 8; i++)
        #pragma unroll
        for (int j = 0; j < 4; j++) {
            v4i z = {0, 0, 0, 0};
            acc[i][j] = z;
        }

    // ---- prologue: prefetch tiles 0,1,2 (12 vmem); wait tile 0 (leave 8 in flight)
    STAGE_A(0, 0); STAGE_B(0, 0);
    STAGE_A(1, 1); STAGE_B(1, 1);
    STAGE_A(2, 2); STAGE_B(2, 2);
    WAITV(8);
    BARRIER();

    #pragma unroll 4
    for (int kt = 0; kt < NT; ++kt) {
        const int buf = kt & 3;
        const int pbuf = (kt + 3) & 3;
        const char* as = As[buf];
        const char* bs = Bs[buf];
        v4i af[4], bf[4], ag[4];

        // ---- phase 0: stage A(t+3) | read m0-3 + B | 16 MFMA
        if (kt < NT - 3) STAGE_A(kt + 3, pbuf);
        #pragma unroll
        for (int i = 0; i < 4; ++i) af[i] = *(const v4i*)&as[aoff + i * 1024];
        #pragma unroll
        for (int j = 0; j < 4; ++j) bf[j] = *(const v4i*)&bs[boff + j * 1024];
        BARRIER();
        __builtin_amdgcn_s_setprio(1);
        #pragma unroll
        for (int i = 0; i < 4; ++i)
            #pragma unroll
            for (int j = 0; j < 4; ++j)
                acc[i][j] = __builtin_amdgcn_mfma_i32_16x16x64_i8(af[i], bf[j], acc[i][j], 0, 0, 0);
        __builtin_amdgcn_s_setprio(0);
        BARRIER();

        // ---- phase 1: stage B(t+3) | read m4-7 | 16 MFMA | counted vmcnt
        if (kt < NT - 3) STAGE_B(kt + 3, pbuf);
        #pragma unroll
        for (int i = 0; i < 4; ++i) ag[i] = *(const v4i*)&as[aoff + 4096 + i * 1024];
        BARRIER();
        __builtin_amdgcn_s_setprio(1);
        #pragma unroll
        for (int i = 0; i < 4; ++i)
            #pragma unroll
            for (int j = 0; j < 4; ++j)
                acc[4 + i][j] = __builtin_amdgcn_mfma_i32_16x16x64_i8(ag[i], bf[j], acc[4 + i][j], 0, 0, 0);
        __builtin_amdgcn_s_setprio(0);

        // next iteration needs tile kt+1 fully landed; keep 2 tiles (8 loads) in flight
        if (kt < NT - 3)       { WAITV(8); }
        else if (kt == NT - 3) { WAITV(4); }
        else if (kt == NT - 2) { WAITV(0); }
        if (kt < NT - 1) BARRIER();
    }

    // ---- epilogue (same verified C/D mapping: col = lane&15, row = (lane>>4)*4 + reg)
    const float gamma = fmaxf((float)(*gsum * (1.0 / 67108864.0)), 1e-6f);
    #pragma unroll
    for (int i = 0; i < 8; ++i) {
        const int brow = m0 + wm * 128 + i * 16 + kq * 4;
        #pragma unroll
        for (int r = 0; r < 4; ++r) {
            const int grow = brow + r;
            const float sv = scales[grow] * gamma;
            #pragma unroll
            for (int j = 0; j < 4; ++j) {
                const int gcol = n0 + wn * 64 + j * 16 + r16;
                C[(size_t)grow * N_DIM + gcol] = sv * (float)acc[i][j][r];
            }
        }
    }
#undef STAGE_A
#undef STAGE_B
}

extern "C" void kernel_launch(void* const* d_in, const int* in_sizes, int n_in,
                              void* d_out, int out_size, void* d_ws, size_t ws_size,
                              hipStream_t stream) {
    const float* x = (const float*)d_in[0];
    const float* w = (const float*)d_in[1];
    float* out = (float*)d_out;
    char* ws = (char*)d_ws;

    double* gsum = (double*)(ws + WS_GSUM);
    float* scales = (float*)(ws + WS_SCALES);
    char* xq = ws + WS_XQ;
    char* wq = ws + WS_WQ;

    hipMemsetAsync(gsum, 0, sizeof(double), stream);
    k_gamma<<<2048, 256, 0, stream>>>((const float4*)w, gsum);
    k_wq<<<4096, 256, 0, stream>>>((const float4*)w, gsum, (int*)wq);
    k_xq<<<M_DIM, 256, 0, stream>>>((const float4*)x, (int*)xq, scales);
    k_gemm<<<dim3(N_DIM / 256, M_DIM / 256), 512, 0, stream>>>(xq, wq, scales, gsum, out);
}